// Round 1
// baseline (419.345 us; speedup 1.0000x reference)
//
#include <hip/hip_runtime.h>

#define NSTATES 64

__global__ __launch_bounds__(256) void diag_logmatexp_kernel(
    const float* __restrict__ xx,
    const float* __restrict__ diag,
    float* __restrict__ out,
    int B)
{
    __shared__ float sh_ed[NSTATES];   // exp(diag[i]) - 1
    const int tid = threadIdx.x;
    if (tid < NSTATES) sh_ed[tid] = __expf(diag[tid]) - 1.0f;
    __syncthreads();

    const long long stride = (long long)gridDim.x * blockDim.x;
    for (long long j = (long long)blockIdx.x * blockDim.x + tid; j < B; j += stride) {
        float v[NSTATES];

        // Load the column (coalesced across lanes for each k).
        #pragma unroll
        for (int k = 0; k < NSTATES; ++k)
            v[k] = xx[(size_t)k * (size_t)B + (size_t)j];

        // Column max.
        float m = v[0];
        #pragma unroll
        for (int k = 1; k < NSTATES; ++k)
            m = fmaxf(m, v[k]);

        // S = sum_k exp(v[k]-m); overwrite v[k] with exp(v[k]-m).
        float S = 0.0f;
        #pragma unroll
        for (int k = 0; k < NSTATES; ++k) {
            float e = __expf(v[k] - m);
            v[k] = e;
            S += e;
        }

        // out[i,j] = m + log(S + e_i * (exp(diag[i]) - 1))
        #pragma unroll
        for (int i = 0; i < NSTATES; ++i) {
            float t = S + v[i] * sh_ed[i];
            out[(size_t)i * (size_t)B + (size_t)j] = m + __logf(t);
        }
    }
}

extern "C" void kernel_launch(void* const* d_in, const int* in_sizes, int n_in,
                              void* d_out, int out_size, void* d_ws, size_t ws_size,
                              hipStream_t stream) {
    const float* xx   = (const float*)d_in[0];
    const float* diag = (const float*)d_in[1];
    float* out = (float*)d_out;

    const int B = in_sizes[0] / NSTATES;   // xx is [64, B]

    const int block = 256;
    int grid = 2048;                        // grid-stride; 256 CUs x 8 blocks
    const long long total = ((long long)B + block - 1) / block;
    if (total < grid) grid = (int)total;

    diag_logmatexp_kernel<<<grid, block, 0, stream>>>(xx, diag, out, B);
}